// Round 3
// baseline (114.288 us; speedup 1.0000x reference)
//
#include <hip/hip_runtime.h>

// Problem constants (match reference)
#define Bn 16
#define Kn 17
#define Hn 256
#define Wn 256
#define Mn 30
#define NFLAT (Kn * Hn * Wn)                   // 1,114,112 tags per image
#define TOTAL ((long long)Bn * Kn * Hn * Wn)   // 17,825,792 elements
#define NVEC  ((int)(TOTAL / 4))               // float4 count = 4,456,448

#define HEAT_BLOCKS 2176                       // 2176*256*8 == NVEC exactly
#define THREADS 256
#define PER_THREAD 8
#define AE_BLOCKS Bn
#define NBLOCKS (HEAT_BLOCKS + AE_BLOCKS)

// ws layout (floats): [0] counter (uint), [64..) partial[HEAT_BLOCKS],
// then push[Bn], pull[Bn]
#define WS_PARTIAL 64
#define WS_PUSH (WS_PARTIAL + HEAT_BLOCKS)
#define WS_PULL (WS_PUSH + Bn)

// ---------------------------------------------------------------------------
// Single fused kernel: heat MSE partials + AE loss + last-block finalize
// ---------------------------------------------------------------------------
__global__ __launch_bounds__(THREADS) void fused_kernel(
    const float4* __restrict__ pred,
    const float4* __restrict__ gt,
    const float4* __restrict__ mask,
    const float* __restrict__ tags,      // [B, NFLAT]
    const int* __restrict__ joints,      // [B, M, K, 2]
    float* __restrict__ ws,              // workspace (counter + partials)
    float* __restrict__ out) {           // [3]
    __shared__ float smem[64];
    __shared__ int is_last;

    unsigned int* counter = (unsigned int*)ws;
    float* partial  = ws + WS_PARTIAL;
    float* push_arr = ws + WS_PUSH;
    float* pull_arr = ws + WS_PULL;

    if (blockIdx.x < HEAT_BLOCKS) {
        // ---------------- heatmap MSE partial (exact partition) -------------
        int t = blockIdx.x * THREADS + threadIdx.x;
        const int stride = HEAT_BLOCKS * THREADS;  // 557,056
        float acc = 0.f;
#pragma unroll
        for (int u = 0; u < PER_THREAD; ++u) {
            int i = u * stride + t;
            float4 p = pred[i];
            float4 g = gt[i];
            float4 m = mask[i];
            float dx = p.x - g.x, dy = p.y - g.y, dz = p.z - g.z, dw = p.w - g.w;
            acc += dx * dx * m.x + dy * dy * m.y + dz * dz * m.z + dw * dw * m.w;
        }
        // intra-wave reduce (64 lanes)
        for (int off = 32; off > 0; off >>= 1) acc += __shfl_down(acc, off, 64);
        int wave = threadIdx.x >> 6;
        if ((threadIdx.x & 63) == 0) smem[wave] = acc;
        __syncthreads();
        if (threadIdx.x == 0)
            partial[blockIdx.x] = smem[0] + smem[1] + smem[2] + smem[3];
    } else {
        // ---------------- AE (push/pull) loss, one image per block ----------
        int b = blockIdx.x - HEAT_BLOCKS;
        int lane = threadIdx.x;  // only wave 0 (lanes 0..63) participates

        float mu = 0.f, pullpp = 0.f, validf = 0.f;
        if (lane < Mn) {
            const int* jb = joints + ((long long)(b * Mn + lane) * Kn) * 2;
            const float* tb = tags + (long long)b * NFLAT;
            float t[Kn], v[Kn];
            float cnt = 0.f, st = 0.f;
#pragma unroll
            for (int k = 0; k < Kn; k++) {
                int id = jb[2 * k];
                int vi = jb[2 * k + 1];
                float tv = tb[id];
                t[k] = tv;
                v[k] = (vi > 0) ? 1.f : 0.f;
                cnt += v[k];
                st += v[k] * tv;
            }
            float sc = fmaxf(cnt, 1.f);
            mu = st / sc;
            float pp = 0.f;
#pragma unroll
            for (int k = 0; k < Kn; k++) {
                float d = t[k] - mu;
                pp += v[k] * d * d;
            }
            pullpp = pp / sc;
            validf = (cnt > 0.f) ? 1.f : 0.f;
            smem[lane] = mu;          // mu in smem[0..29]
            smem[32 + lane] = validf; // valid in smem[32..61]
        }
        __syncthreads();

        if (lane < 64) {
            float nv = validf;
            float pv = (validf > 0.f) ? pullpp : 0.f;
            float sm = 0.f;
            if (lane < Mn && validf > 0.f) {
                for (int j = 0; j < Mn; j++) {
                    if (smem[32 + j] > 0.f) {
                        float d = mu - smem[j];
                        sm += expf(-(d * d));
                    }
                }
            }
            for (int off = 32; off > 0; off >>= 1) {
                nv += __shfl_down(nv, off, 64);
                pv += __shfl_down(pv, off, 64);
                sm += __shfl_down(sm, off, 64);
            }
            if (lane == 0) {
                float n = nv;
                float pull = pv / fmaxf(n, 1.f);
                float denom = fmaxf((n - 1.f) * n, 1.f);
                float push = (n >= 2.f) ? (sm - n) / denom * 0.5f : 0.f;
                push_arr[b] = push;
                pull_arr[b] = pull;
            }
        }
    }

    // ---------------- last-block-done finalize ------------------------------
    if (threadIdx.x == 0) {
        __threadfence();  // release: partial/push/pull visible before ticket
        unsigned int ticket = atomicAdd(counter, 1u);
        is_last = (ticket == (unsigned int)(NBLOCKS - 1)) ? 1 : 0;
    }
    __syncthreads();
    if (is_last) {
        __threadfence();  // acquire: see all other blocks' writes
        __shared__ double sd[THREADS];
        double acc = 0.0;
        for (int i = threadIdx.x; i < HEAT_BLOCKS; i += THREADS)
            acc += (double)partial[i];
        sd[threadIdx.x] = acc;
        __syncthreads();
        for (int off = THREADS / 2; off > 0; off >>= 1) {
            if (threadIdx.x < off) sd[threadIdx.x] += sd[threadIdx.x + off];
            __syncthreads();
        }
        if (threadIdx.x == 0) {
            double heat = sd[0] / (double)TOTAL;   // HEATMAPS_LOSS_FACTOR = 1.0
            float psum = 0.f, lsum = 0.f;
            for (int b = 0; b < Bn; b++) {
                psum += push_arr[b];
                lsum += pull_arr[b];
            }
            out[0] = (float)heat;
            out[1] = (psum / (float)Bn) * 0.001f;  // PUSH_LOSS_FACTOR
            out[2] = (lsum / (float)Bn) * 0.001f;  // PULL_LOSS_FACTOR
        }
    }
}

// ---------------------------------------------------------------------------
extern "C" void kernel_launch(void* const* d_in, const int* in_sizes, int n_in,
                              void* d_out, int out_size, void* d_ws, size_t ws_size,
                              hipStream_t stream) {
    const float* heatmaps_pred = (const float*)d_in[0];
    const float* heatmaps      = (const float*)d_in[1];
    const float* masks         = (const float*)d_in[2];
    const float* tags_pred     = (const float*)d_in[3];
    const int*   joints        = (const int*)d_in[4];
    float* out = (float*)d_out;
    float* ws  = (float*)d_ws;

    // zero the ticket counter (graph-capture-safe async memset, 4 bytes)
    hipMemsetAsync(d_ws, 0, sizeof(unsigned int), stream);

    fused_kernel<<<NBLOCKS, THREADS, 0, stream>>>(
        (const float4*)heatmaps_pred, (const float4*)heatmaps,
        (const float4*)masks, tags_pred, joints, ws, out);
}

// Round 4
// 41.752 us; speedup vs baseline: 2.7373x; 2.7373x over previous
//
#include <hip/hip_runtime.h>

// Problem constants (match reference)
#define Bn 16
#define Kn 17
#define Hn 256
#define Wn 256
#define Mn 30
#define NFLAT (Kn * Hn * Wn)                   // 1,114,112 tags per image
#define TOTAL ((long long)Bn * Kn * Hn * Wn)   // 17,825,792 elements
#define NVEC  ((int)(TOTAL / 4))               // float4 count = 4,456,448

#define HEAT_BLOCKS 2176                       // 2176*256*8 == NVEC exactly
#define THREADS 256
#define GROUPS 2                               // outer iterations
#define VPG 4                                  // float4s per group (consecutive)
#define AE_BLOCKS Bn
#define NBLOCKS (HEAT_BLOCKS + AE_BLOCKS)
#define TSTRIDE (HEAT_BLOCKS * THREADS)        // 557,056 threads

// ---------------------------------------------------------------------------
// Kernel 1: AE blocks [0,16) + heat MSE partial blocks [16, 16+2176)
// ---------------------------------------------------------------------------
__global__ __launch_bounds__(THREADS) void fused_kernel(
    const float4* __restrict__ pred,
    const float4* __restrict__ gt,
    const float4* __restrict__ mask,
    const float* __restrict__ tags,      // [B, NFLAT]
    const int* __restrict__ joints,      // [B, M, K, 2]
    float* __restrict__ partial,         // [HEAT_BLOCKS]
    float* __restrict__ push_arr,        // [Bn]
    float* __restrict__ pull_arr) {      // [Bn]
    __shared__ float smem[64];

    if (blockIdx.x >= AE_BLOCKS) {
        // ---------------- heatmap MSE partial (exact partition) -------------
        int hb = blockIdx.x - AE_BLOCKS;
        int t = hb * THREADS + threadIdx.x;
        float acc0 = 0.f, acc1 = 0.f, acc2 = 0.f, acc3 = 0.f;
#pragma unroll
        for (int g = 0; g < GROUPS; ++g) {
            int base = (g * TSTRIDE + t) * VPG;   // 4 consecutive float4s
            float4 p0 = pred[base + 0], p1 = pred[base + 1];
            float4 p2 = pred[base + 2], p3 = pred[base + 3];
            float4 g0 = gt[base + 0],   g1 = gt[base + 1];
            float4 g2 = gt[base + 2],   g3 = gt[base + 3];
            float4 m0 = mask[base + 0], m1 = mask[base + 1];
            float4 m2 = mask[base + 2], m3 = mask[base + 3];
            float dx, dy, dz, dw;
            dx = p0.x - g0.x; dy = p0.y - g0.y; dz = p0.z - g0.z; dw = p0.w - g0.w;
            acc0 += dx * dx * m0.x + dy * dy * m0.y + dz * dz * m0.z + dw * dw * m0.w;
            dx = p1.x - g1.x; dy = p1.y - g1.y; dz = p1.z - g1.z; dw = p1.w - g1.w;
            acc1 += dx * dx * m1.x + dy * dy * m1.y + dz * dz * m1.z + dw * dw * m1.w;
            dx = p2.x - g2.x; dy = p2.y - g2.y; dz = p2.z - g2.z; dw = p2.w - g2.w;
            acc2 += dx * dx * m2.x + dy * dy * m2.y + dz * dz * m2.z + dw * dw * m2.w;
            dx = p3.x - g3.x; dy = p3.y - g3.y; dz = p3.z - g3.z; dw = p3.w - g3.w;
            acc3 += dx * dx * m3.x + dy * dy * m3.y + dz * dz * m3.z + dw * dw * m3.w;
        }
        float a = (acc0 + acc1) + (acc2 + acc3);
        // intra-wave reduce (64 lanes)
        for (int off = 32; off > 0; off >>= 1) a += __shfl_down(a, off, 64);
        int wave = threadIdx.x >> 6;
        if ((threadIdx.x & 63) == 0) smem[wave] = a;
        __syncthreads();
        if (threadIdx.x == 0)
            partial[hb] = smem[0] + smem[1] + smem[2] + smem[3];
    } else {
        // ---------------- AE (push/pull) loss, one image per block ----------
        int b = blockIdx.x;
        int lane = threadIdx.x;  // only wave 0 (lanes 0..63) participates

        float mu = 0.f, pullpp = 0.f, validf = 0.f;
        if (lane < Mn) {
            const int* jb = joints + ((long long)(b * Mn + lane) * Kn) * 2;
            const float* tb = tags + (long long)b * NFLAT;
            float t[Kn], v[Kn];
            float cnt = 0.f, st = 0.f;
#pragma unroll
            for (int k = 0; k < Kn; k++) {
                int id = jb[2 * k];
                int vi = jb[2 * k + 1];
                float tv = tb[id];
                t[k] = tv;
                v[k] = (vi > 0) ? 1.f : 0.f;
                cnt += v[k];
                st += v[k] * tv;
            }
            float sc = fmaxf(cnt, 1.f);
            mu = st / sc;
            float pp = 0.f;
#pragma unroll
            for (int k = 0; k < Kn; k++) {
                float d = t[k] - mu;
                pp += v[k] * d * d;
            }
            pullpp = pp / sc;
            validf = (cnt > 0.f) ? 1.f : 0.f;
            smem[lane] = mu;          // mu in smem[0..29]
            smem[32 + lane] = validf; // valid in smem[32..61]
        }
        __syncthreads();

        if (lane < 64) {
            float nv = validf;
            float pv = (validf > 0.f) ? pullpp : 0.f;
            float sm = 0.f;
            if (lane < Mn && validf > 0.f) {
                for (int j = 0; j < Mn; j++) {
                    if (smem[32 + j] > 0.f) {
                        float d = mu - smem[j];
                        sm += expf(-(d * d));
                    }
                }
            }
            for (int off = 32; off > 0; off >>= 1) {
                nv += __shfl_down(nv, off, 64);
                pv += __shfl_down(pv, off, 64);
                sm += __shfl_down(sm, off, 64);
            }
            if (lane == 0) {
                float n = nv;
                float pull = pv / fmaxf(n, 1.f);
                float denom = fmaxf((n - 1.f) * n, 1.f);
                float push = (n >= 2.f) ? (sm - n) / denom * 0.5f : 0.f;
                push_arr[b] = push;
                pull_arr[b] = pull;
            }
        }
    }
}

// ---------------------------------------------------------------------------
// Kernel 2: finalize — reduce partials (double) + average push/pull
// ---------------------------------------------------------------------------
__global__ __launch_bounds__(256) void finalize_kernel(
    const float* __restrict__ partial,
    const float* __restrict__ push_arr,
    const float* __restrict__ pull_arr,
    float* __restrict__ out) {
    __shared__ double sd[256];
    double acc = 0.0;
    for (int i = threadIdx.x; i < HEAT_BLOCKS; i += 256) acc += (double)partial[i];
    sd[threadIdx.x] = acc;
    __syncthreads();
    for (int off = 128; off > 0; off >>= 1) {
        if (threadIdx.x < off) sd[threadIdx.x] += sd[threadIdx.x + off];
        __syncthreads();
    }
    if (threadIdx.x == 0) {
        double heat = sd[0] / (double)TOTAL;       // HEATMAPS_LOSS_FACTOR = 1.0
        float psum = 0.f, lsum = 0.f;
        for (int b = 0; b < Bn; b++) {
            psum += push_arr[b];
            lsum += pull_arr[b];
        }
        out[0] = (float)heat;
        out[1] = (psum / (float)Bn) * 0.001f;      // PUSH_LOSS_FACTOR
        out[2] = (lsum / (float)Bn) * 0.001f;      // PULL_LOSS_FACTOR
    }
}

// ---------------------------------------------------------------------------
extern "C" void kernel_launch(void* const* d_in, const int* in_sizes, int n_in,
                              void* d_out, int out_size, void* d_ws, size_t ws_size,
                              hipStream_t stream) {
    const float* heatmaps_pred = (const float*)d_in[0];
    const float* heatmaps      = (const float*)d_in[1];
    const float* masks         = (const float*)d_in[2];
    const float* tags_pred     = (const float*)d_in[3];
    const int*   joints        = (const int*)d_in[4];
    float* out = (float*)d_out;

    float* ws = (float*)d_ws;
    float* partial  = ws;                 // [HEAT_BLOCKS]
    float* push_arr = ws + HEAT_BLOCKS;   // [Bn]
    float* pull_arr = push_arr + Bn;      // [Bn]

    fused_kernel<<<NBLOCKS, THREADS, 0, stream>>>(
        (const float4*)heatmaps_pred, (const float4*)heatmaps,
        (const float4*)masks, tags_pred, joints, partial, push_arr, pull_arr);

    finalize_kernel<<<1, 256, 0, stream>>>(partial, push_arr, pull_arr, out);
}